// Round 10
// baseline (220.389 us; speedup 1.0000x reference)
//
#include <hip/hip_runtime.h>

#define B_SZ    64
#define S_LEN   448
#define D_MODEL 1024
#define N_HEAD  16
#define D_HEAD  64
#define CHUNK   28
#define NCH     16    // 16 * 28 = 448
#define PF      8
#define CPY_BLK 2048

typedef float f4 __attribute__((ext_vector_type(4)));

// ---------------------------------------------------------------------------
// GEMM partial: P[(mat*8+kt)][b][n] = sum_{k in kt-range} X[b][k] * W[k][n]
// ---------------------------------------------------------------------------
__global__ __launch_bounds__(256) void gemm_part(
    const float* __restrict__ X,
    const float* __restrict__ W0, const float* __restrict__ W1,
    const float* __restrict__ W2,
    float* __restrict__ P)
{
    const int nt  = blockIdx.x;
    const int kt  = blockIdx.y;
    const int mat = blockIdx.z;
    const float* __restrict__ W = (mat == 0) ? W0 : ((mat == 1) ? W1 : W2);

    const int t  = threadIdx.x;
    const int n  = nt * 64 + (t & 63);
    const int b0 = __builtin_amdgcn_readfirstlane((t >> 6) * 16);
    const int k0 = kt * 128;

    float acc[16];
#pragma unroll
    for (int j = 0; j < 16; ++j) acc[j] = 0.f;

#pragma unroll 8
    for (int k = k0; k < k0 + 128; ++k) {
        const float w = W[k * D_MODEL + n];
#pragma unroll
        for (int j = 0; j < 16; ++j)
            acc[j] += X[(b0 + j) * D_MODEL + k] * w;
    }

    float* p = P + (size_t)(mat * 8 + kt) * (B_SZ * D_MODEL);
#pragma unroll
    for (int j = 0; j < 16; ++j)
        p[(b0 + j) * D_MODEL + n] = acc[j];
}

// reduce 8 k-partials + bias -> final out projection
__global__ __launch_bounds__(256) void reduce_out(
    const float* __restrict__ P, const float* __restrict__ bo,
    float* __restrict__ out)
{
    const int i = blockIdx.x * 256 + threadIdx.x;     // < 65536
    float s = bo[i & (D_MODEL - 1)];
#pragma unroll
    for (int kt = 0; kt < 8; ++kt)
        s += P[(size_t)kt * 65536 + i];
    out[i] = s;
}

// ---------------------------------------------------------------------------
// Attention partials, READ-ONLY. grid = (NCH, B), block = 256.
// ---------------------------------------------------------------------------
__global__ __launch_bounds__(256) void attn_read(
    const float* __restrict__ kcache, const float* __restrict__ vcache,
    const float* __restrict__ part,   // [24][64][1024]: q 0-7, k 8-15, v 16-23
    const float* __restrict__ bq, const float* __restrict__ bv,
    const float* __restrict__ amask, const int* __restrict__ idxp,
    float* __restrict__ accws, float* __restrict__ mlws)
{
    const int c   = blockIdx.x;
    const int b   = blockIdx.y;
    const int t   = threadIdx.x;
    const int col = t * 4;
    const int h   = t >> 4;
    const int l16 = t & 15;
    const int idx = idxp[0];
    const int s0  = c * CHUNK;

    f4 q = *(const f4*)(bq + col);
#pragma unroll
    for (int kt = 0; kt < 8; ++kt)
        q += *(const f4*)(part + (size_t)kt * 65536 + b * D_MODEL + col);

    f4 knew = (f4)0.f, vnew = (f4)0.f;
    if ((idx >= s0) && (idx < s0 + CHUNK)) {
#pragma unroll
        for (int kt = 0; kt < 8; ++kt) {
            knew += *(const f4*)(part + (size_t)(8 + kt)  * 65536 + b * D_MODEL + col);
            vnew += *(const f4*)(part + (size_t)(16 + kt) * 65536 + b * D_MODEL + col);
        }
        vnew += *(const f4*)(bv + col);
    }

    const size_t base = (size_t)(b * S_LEN + s0) * D_MODEL + col;

    f4 kb[PF], vb[PF];
#pragma unroll
    for (int r = 0; r < PF; ++r) {
        kb[r] = *(const f4*)(kcache + base + (size_t)r * D_MODEL);
        vb[r] = *(const f4*)(vcache + base + (size_t)r * D_MODEL);
    }

    float m = -1e30f, l = 0.f;
    f4 acc = (f4)0.f;

#pragma unroll
    for (int s = 0; s < CHUNK; ++s) {
        f4 k4 = kb[s & (PF - 1)];
        f4 v4 = vb[s & (PF - 1)];
        if (s + PF < CHUNK) {
            kb[s & (PF - 1)] = *(const f4*)(kcache + base + (size_t)(s + PF) * D_MODEL);
            vb[s & (PF - 1)] = *(const f4*)(vcache + base + (size_t)(s + PF) * D_MODEL);
        }
        const int srow = s0 + s;
        if (srow == idx) { k4 = knew; v4 = vnew; }

        float p = q.x * k4.x + q.y * k4.y + q.z * k4.z + q.w * k4.w;
        p += __shfl_xor(p, 1);
        p += __shfl_xor(p, 2);
        p += __shfl_xor(p, 4);
        p += __shfl_xor(p, 8);
        p = p * 0.125f + amask[srow];

        const float mn = fmaxf(m, p);
        const float f  = __expf(m - mn);
        const float w  = __expf(p - mn);
        l = l * f + w;
        acc.x = acc.x * f + w * v4.x;
        acc.y = acc.y * f + w * v4.y;
        acc.z = acc.z * f + w * v4.z;
        acc.w = acc.w * f + w * v4.w;
        m = mn;
    }

    float* ap = accws + ((size_t)(b * N_HEAD + h) * NCH + c) * D_HEAD + l16 * 4;
    *(f4*)ap = acc;
    if (l16 == 0) {
        const int w = (b * N_HEAD + h) * NCH + c;
        mlws[w * 2]     = m;
        mlws[w * 2 + 1] = l;
    }
}

// pure grid-stride copy, PLAIN stores
__global__ __launch_bounds__(256) void copy_plain(
    const float* __restrict__ src, float* __restrict__ dst)
{
    const size_t n4     = (size_t)B_SZ * S_LEN * D_MODEL / 4;  // 7,340,032
    const size_t stride = (size_t)CPY_BLK * 256;
    const f4* __restrict__ s = (const f4*)src;
    f4* __restrict__ d = (f4*)dst;
    size_t i = (size_t)blockIdx.x * 256 + threadIdx.x;
#pragma unroll 7
    for (; i < n4; i += stride) d[i] = s[i];
}

// pure grid-stride copy, NT stores
__global__ __launch_bounds__(256) void copy_nt(
    const float* __restrict__ src, float* __restrict__ dst)
{
    const size_t n4     = (size_t)B_SZ * S_LEN * D_MODEL / 4;
    const size_t stride = (size_t)CPY_BLK * 256;
    const f4* __restrict__ s = (const f4*)src;
    f4* __restrict__ d = (f4*)dst;
    size_t i = (size_t)blockIdx.x * 256 + threadIdx.x;
#pragma unroll 7
    for (; i < n4; i += stride) __builtin_nontemporal_store(s[i], d + i);
}

// overwrite row idx of kout/vout with the new token's k/v (partials 8-23)
__global__ __launch_bounds__(256) void kv_fix(
    const float* __restrict__ part, const float* __restrict__ bv,
    const int* __restrict__ idxp,
    float* __restrict__ kout, float* __restrict__ vout)
{
    const int b   = blockIdx.x;
    const int col = threadIdx.x * 4;
    const int idx = idxp[0];
    f4 kn = (f4)0.f, vn = (f4)0.f;
#pragma unroll
    for (int kt = 0; kt < 8; ++kt) {
        kn += *(const f4*)(part + (size_t)(8 + kt)  * 65536 + b * D_MODEL + col);
        vn += *(const f4*)(part + (size_t)(16 + kt) * 65536 + b * D_MODEL + col);
    }
    vn += *(const f4*)(bv + col);
    const size_t roff = (size_t)(b * S_LEN + idx) * D_MODEL + col;
    *(f4*)(kout + roff) = kn;
    *(f4*)(vout + roff) = vn;
}

// combine chunk partials -> wv[b][h*64+d]
__global__ __launch_bounds__(256) void combine(
    const float* __restrict__ accws, const float* __restrict__ mlws,
    float* __restrict__ wvws)
{
    const int t = threadIdx.x;
    const int w = blockIdx.x * 4 + (t >> 6);   // (b*16+h), 0..1023
    const int d = t & 63;

    float M = -1e30f;
#pragma unroll
    for (int c = 0; c < NCH; ++c)
        M = fmaxf(M, mlws[(w * NCH + c) * 2]);
    float L = 0.f, O = 0.f;
#pragma unroll
    for (int c = 0; c < NCH; ++c) {
        const float f = __expf(mlws[(w * NCH + c) * 2] - M);
        L += mlws[(w * NCH + c) * 2 + 1] * f;
        O += accws[(w * NCH + c) * D_HEAD + d] * f;
    }
    const int b = w >> 4, h = w & 15;
    wvws[b * D_MODEL + h * D_HEAD + d] = O / L;
}

// ---------------------------------------------------------------------------
extern "C" void kernel_launch(void* const* d_in, const int* in_sizes, int n_in,
                              void* d_out, int out_size, void* d_ws, size_t ws_size,
                              hipStream_t stream) {
    const float* x      = (const float*)d_in[0];
    const float* kcache = (const float*)d_in[1];
    const float* vcache = (const float*)d_in[2];
    const int*   idxp   = (const int*)d_in[3];
    const float* amask  = (const float*)d_in[4];
    const float* Wq     = (const float*)d_in[5];
    const float* bq     = (const float*)d_in[6];
    const float* Wk     = (const float*)d_in[7];
    const float* Wv     = (const float*)d_in[8];
    const float* bv     = (const float*)d_in[9];
    const float* Wo     = (const float*)d_in[10];
    const float* bo     = (const float*)d_in[11];

    float* out  = (float*)d_out;                 // [64][1024]
    float* kout = out + 65536;                   // [64][448][1024]
    float* vout = kout + (size_t)B_SZ * S_LEN * D_MODEL;

    float* ws    = (float*)d_ws;
    float* part  = ws;                 // 24*65536 = 1572864
    float* accws = ws + 1572864;       // 1048576
    float* mlws  = ws + 2621440;       // 32768
    float* wvws  = ws + 2654208;       // 65536

    // projections
    gemm_part<<<dim3(16, 8, 3), 256, 0, stream>>>(x, Wq, Wk, Wv, part);

    // attention partials — read-only pass (own rocprof row)
    attn_read<<<dim3(NCH, B_SZ), 256, 0, stream>>>(
        kcache, vcache, part, bq, bv, amask, idxp, accws, mlws);

    // softmax combine -> wv
    combine<<<256, 256, 0, stream>>>(accws, mlws, wvws);

    // output projection (mat=0 writes part slots 0-7 only; 8-23 intact)
    gemm_part<<<dim3(16, 8, 1), 256, 0, stream>>>(wvws, Wo, Wo, Wo, part);
    reduce_out<<<256, 256, 0, stream>>>(part, bo, out);

    // the two copy primitives, separately instrumented
    copy_plain<<<CPY_BLK, 256, 0, stream>>>(kcache, kout);
    copy_nt   <<<CPY_BLK, 256, 0, stream>>>(vcache, vout);

    // idx-row fixup
    kv_fix<<<B_SZ, 256, 0, stream>>>(part, bv, idxp, kout, vout);
}

// Round 11
// 177.532 us; speedup vs baseline: 1.2414x; 1.2414x over previous
//
#include <hip/hip_runtime.h>

#define B_SZ    64
#define S_LEN   448
#define D_MODEL 1024
#define N_HEAD  16
#define D_HEAD  64
#define NBLK    32    // blocks per batch for stream passes; 448 = 32*14 rows
#define NROW    14

typedef float f4 __attribute__((ext_vector_type(4)));

// ws layout (float offsets)
#define PARTU_OFF  0          // 24*65536 = 1,572,864 (gemm k-split partials)
#define QKV_OFF    1572864    // [3][64][1024] (q+bq, knew, vnew+bv)
#define SCORE_OFF  1769472    // [64][448][16] = 458,752
#define VPART_OFF  2228224    // [2048][1024]  = 2,097,152
#define WV_OFF     4325376    // 65,536   (total ~17.6 MB)

// ---------------------------------------------------------------------------
// GEMM partial: P[(mat*8+kt)][b][n] = sum_{k in kt-range} X[b][k] * W[k][n]
// ---------------------------------------------------------------------------
__global__ __launch_bounds__(256) void gemm_part(
    const float* __restrict__ X,
    const float* __restrict__ W0, const float* __restrict__ W1,
    const float* __restrict__ W2,
    float* __restrict__ P)
{
    const int nt  = blockIdx.x;
    const int kt  = blockIdx.y;
    const int mat = blockIdx.z;
    const float* __restrict__ W = (mat == 0) ? W0 : ((mat == 1) ? W1 : W2);

    const int t  = threadIdx.x;
    const int n  = nt * 64 + (t & 63);
    const int b0 = __builtin_amdgcn_readfirstlane((t >> 6) * 16);
    const int k0 = kt * 128;

    float acc[16];
#pragma unroll
    for (int j = 0; j < 16; ++j) acc[j] = 0.f;

#pragma unroll 8
    for (int k = k0; k < k0 + 128; ++k) {
        const float w = W[k * D_MODEL + n];
#pragma unroll
        for (int j = 0; j < 16; ++j)
            acc[j] += X[(b0 + j) * D_MODEL + k] * w;
    }

    float* p = P + (size_t)(mat * 8 + kt) * (B_SZ * D_MODEL);
#pragma unroll
    for (int j = 0; j < 16; ++j)
        p[(b0 + j) * D_MODEL + n] = acc[j];
}

// materialize q(+bq), knew, vnew(+bv) from the k-split partials
__global__ __launch_bounds__(256) void prep(
    const float* __restrict__ P, const float* __restrict__ bq,
    const float* __restrict__ bv, float* __restrict__ qkv)
{
    const int i   = blockIdx.x * 256 + threadIdx.x;   // < 196608
    const int mat = i >> 16;
    const int r   = i & 65535;
    const int d   = r & (D_MODEL - 1);
    float s = (mat == 0) ? bq[d] : ((mat == 2) ? bv[d] : 0.f);
#pragma unroll
    for (int kt = 0; kt < 8; ++kt)
        s += P[(size_t)(mat * 8 + kt) * 65536 + r];
    qkv[i] = s;
}

// reduce 8 k-partials + bias -> final out projection
__global__ __launch_bounds__(256) void reduce_out(
    const float* __restrict__ P, const float* __restrict__ bo,
    float* __restrict__ out)
{
    const int i = blockIdx.x * 256 + threadIdx.x;     // < 65536
    float s = bo[i & (D_MODEL - 1)];
#pragma unroll
    for (int kt = 0; kt < 8; ++kt)
        s += P[(size_t)kt * 65536 + i];
    out[i] = s;
}

// ---------------------------------------------------------------------------
// K pass: copy-shaped. Block (j,b) walks rows j, j+32, ... (dense 8MB window
// across the grid). Per row: copy K (NT) + 16-lane dot -> raw score.
// ---------------------------------------------------------------------------
__global__ __launch_bounds__(256) void kpass(
    const float* __restrict__ kcache, const float* __restrict__ qkv,
    const float* __restrict__ amask, const int* __restrict__ idxp,
    float* __restrict__ kout, float* __restrict__ score)
{
    const int bid = blockIdx.x;
    const int j   = bid & (NBLK - 1);
    const int b   = bid >> 5;
    const int t   = threadIdx.x;
    const int col = t * 4;
    const int h   = t >> 4;
    const int idx = idxp[0];

    const f4 q  = *(const f4*)(qkv + (size_t)b * D_MODEL + col);
    const f4 kn = *(const f4*)(qkv + (size_t)(B_SZ + b) * D_MODEL + col);

#pragma unroll 4
    for (int r = 0; r < NROW; ++r) {
        const int s = j + r * NBLK;
        const size_t ro = ((size_t)b * S_LEN + s) * D_MODEL + col;
        f4 k4 = *(const f4*)(kcache + ro);
        if (s == idx) k4 = kn;
        __builtin_nontemporal_store(k4, (f4*)(kout + ro));
        float d = q.x * k4.x + q.y * k4.y + q.z * k4.z + q.w * k4.w;
        d += __shfl_xor(d, 1);
        d += __shfl_xor(d, 2);
        d += __shfl_xor(d, 4);
        d += __shfl_xor(d, 8);
        if ((t & 15) == 0)
            score[((size_t)b * S_LEN + s) * N_HEAD + h] = d * 0.125f + amask[s];
    }
}

// in-place softmax over s for each (b,h); one wave per (b,h)  (proven in R7)
__global__ __launch_bounds__(256) void softmax_k(float* __restrict__ sc)
{
    const int gw   = blockIdx.x * 4 + (threadIdx.x >> 6);  // 0..1023
    const int b    = gw >> 4;
    const int h    = gw & 15;
    const int lane = threadIdx.x & 63;

    float v[7];
    float mx = -1e30f;
#pragma unroll
    for (int t = 0; t < 7; ++t) {
        v[t] = sc[((size_t)b * S_LEN + lane + t * 64) * N_HEAD + h];
        mx = fmaxf(mx, v[t]);
    }
#pragma unroll
    for (int o = 1; o < 64; o <<= 1) mx = fmaxf(mx, __shfl_xor(mx, o));
    float sum = 0.f;
#pragma unroll
    for (int t = 0; t < 7; ++t) { v[t] = __expf(v[t] - mx); sum += v[t]; }
#pragma unroll
    for (int o = 1; o < 64; o <<= 1) sum += __shfl_xor(sum, o);
    const float inv = 1.f / sum;
#pragma unroll
    for (int t = 0; t < 7; ++t)
        sc[((size_t)b * S_LEN + lane + t * 64) * N_HEAD + h] = v[t] * inv;
}

// ---------------------------------------------------------------------------
// V pass: copy-shaped, same geometry as kpass. Per row: copy V (NT) +
// weighted accumulate with the normalized score. Partial per block.
// ---------------------------------------------------------------------------
__global__ __launch_bounds__(256) void vpass(
    const float* __restrict__ vcache, const float* __restrict__ qkv,
    const float* __restrict__ score, const int* __restrict__ idxp,
    float* __restrict__ vout, float* __restrict__ partial)
{
    const int bid = blockIdx.x;
    const int j   = bid & (NBLK - 1);
    const int b   = bid >> 5;
    const int t   = threadIdx.x;
    const int col = t * 4;
    const int h   = t >> 4;
    const int idx = idxp[0];

    const f4 vn = *(const f4*)(qkv + (size_t)(2 * B_SZ + b) * D_MODEL + col);
    f4 acc = (f4)0.f;

#pragma unroll 4
    for (int r = 0; r < NROW; ++r) {
        const int s = j + r * NBLK;
        const size_t ro = ((size_t)b * S_LEN + s) * D_MODEL + col;
        f4 v4 = *(const f4*)(vcache + ro);
        if (s == idx) v4 = vn;
        __builtin_nontemporal_store(v4, (f4*)(vout + ro));
        const float w = score[((size_t)b * S_LEN + s) * N_HEAD + h];
        acc.x += w * v4.x;
        acc.y += w * v4.y;
        acc.z += w * v4.z;
        acc.w += w * v4.w;
    }

    *(f4*)(partial + (size_t)bid * D_MODEL + col) = acc;
}

// wv[b][d] = sum over the 32 block-partials of batch b
__global__ __launch_bounds__(256) void combine_b(
    const float* __restrict__ partial, float* __restrict__ wv)
{
    const int b   = blockIdx.x;
    const int col = threadIdx.x * 4;
    f4 s = (f4)0.f;
#pragma unroll
    for (int j = 0; j < NBLK; ++j)
        s += *(const f4*)(partial + ((size_t)(b * NBLK + j)) * D_MODEL + col);
    *(f4*)(wv + (size_t)b * D_MODEL + col) = s;
}

// ---------------------------------------------------------------------------
extern "C" void kernel_launch(void* const* d_in, const int* in_sizes, int n_in,
                              void* d_out, int out_size, void* d_ws, size_t ws_size,
                              hipStream_t stream) {
    const float* x      = (const float*)d_in[0];
    const float* kcache = (const float*)d_in[1];
    const float* vcache = (const float*)d_in[2];
    const int*   idxp   = (const int*)d_in[3];
    const float* amask  = (const float*)d_in[4];
    const float* Wq     = (const float*)d_in[5];
    const float* bq     = (const float*)d_in[6];
    const float* Wk     = (const float*)d_in[7];
    const float* Wv     = (const float*)d_in[8];
    const float* bv     = (const float*)d_in[9];
    const float* Wo     = (const float*)d_in[10];
    const float* bo     = (const float*)d_in[11];

    float* out  = (float*)d_out;                 // [64][1024]
    float* kout = out + 65536;                   // [64][448][1024]
    float* vout = kout + (size_t)B_SZ * S_LEN * D_MODEL;

    float* ws    = (float*)d_ws;
    float* partU = ws + PARTU_OFF;
    float* qkv   = ws + QKV_OFF;
    float* score = ws + SCORE_OFF;
    float* vpart = ws + VPART_OFF;
    float* wvws  = ws + WV_OFF;

    // q/k/v projections (k-split partials)
    gemm_part<<<dim3(16, 8, 3), 256, 0, stream>>>(x, Wq, Wk, Wv, partU);

    // q(+bq) / knew / vnew
    prep<<<768, 256, 0, stream>>>(partU, bq, bv, qkv);

    // K copy + raw scores (copy-shaped, dense window)
    kpass<<<B_SZ * NBLK, 256, 0, stream>>>(
        kcache, qkv, amask, idxp, kout, score);

    // softmax in place (1.8 MB, L2-hot)
    softmax_k<<<256, 256, 0, stream>>>(score);

    // V copy + weighted partials (copy-shaped, dense window)
    vpass<<<B_SZ * NBLK, 256, 0, stream>>>(
        vcache, qkv, score, idxp, vout, vpart);

    // sum 32 partials per batch -> wv
    combine_b<<<B_SZ, 256, 0, stream>>>(vpart, wvws);

    // output projection (writes partU slots 0-7; qkv/partials dead by now)
    gemm_part<<<dim3(16, 8, 1), 256, 0, stream>>>(wvws, Wo, Wo, Wo, partU);
    reduce_out<<<256, 256, 0, stream>>>(partU, bo, out);
}